// Round 1
// baseline (277.255 us; speedup 1.0000x reference)
//
#include <hip/hip_runtime.h>
#include <hip/hip_bf16.h>
#include <cstdint>
#include <cmath>

typedef __bf16 bf16_t;
typedef __attribute__((ext_vector_type(8))) __bf16 bf16x8;
typedef __attribute__((ext_vector_type(4))) float f32x4;

#define LOG2E 1.4426950408889634f

constexpr int B_ = 2, T_ = 2048, C_ = 1024, H_ = 16, HD_ = 64, HD2_ = 32;
constexpr int M_ = B_ * T_;  // 4096

static __device__ __forceinline__ f32x4 mfma16(bf16x8 a, bf16x8 b, f32x4 c) {
    return __builtin_amdgcn_mfma_f32_16x16x32_bf16(a, b, c, 0, 0, 0);
}

// ---------------- prep kernels ----------------
__global__ void cast_f32_to_bf16(const float* __restrict__ in, bf16_t* __restrict__ out, int n4) {
    int i = blockIdx.x * blockDim.x + threadIdx.x;
    if (i < n4) {
        float4 v = ((const float4*)in)[i];
        bf16_t o[4] = {(bf16_t)v.x, (bf16_t)v.y, (bf16_t)v.z, (bf16_t)v.w};
        *(uint64_t*)(out + (size_t)i * 4) = *(uint64_t*)o;
    }
}

// W [K][N] fp32 row-major  ->  WT [N][K] bf16
__global__ void transpose_cast(const float* __restrict__ W, bf16_t* __restrict__ WT, int K, int N) {
    __shared__ float tile[32][33];
    int nb = blockIdx.x * 32, kb = blockIdx.y * 32;
    for (int i = threadIdx.y; i < 32; i += 8)
        tile[i][threadIdx.x] = W[(size_t)(kb + i) * N + nb + threadIdx.x];
    __syncthreads();
    for (int i = threadIdx.y; i < 32; i += 8)
        WT[(size_t)(nb + i) * K + kb + threadIdx.x] = (bf16_t)tile[threadIdx.x][i];
}

// ---------------- GEMM: C[m][n] = A[m][:] . BT[n][:] + bias ----------------
// MODE 0: qkv epilogue (bias + RoPE(q,k) + q*0.125, scatter to Qb/Kb[B,H,T,64], V -> VTb[B,H,64,T])
// MODE 1: plain fp32 out + bias
template <int MODE>
__global__ __launch_bounds__(256, 2) void gemm128(
    const bf16_t* __restrict__ A, const bf16_t* __restrict__ BT, const float* __restrict__ bias,
    int N, int K,
    bf16_t* __restrict__ Qb, bf16_t* __restrict__ Kb, bf16_t* __restrict__ VTb,
    const float* __restrict__ cosT, const float* __restrict__ sinT, float* __restrict__ out) {
    __shared__ alignas(16) bf16_t As[128 * 32];
    __shared__ alignas(16) bf16_t Bs[128 * 32];
    const int tid = threadIdx.x;
    const int w = tid >> 6, lane = tid & 63;
    const int quad = lane >> 4, r = lane & 15;
    const int wm = (w >> 1) * 64, wn = (w & 1) * 64;
    const int mb = blockIdx.y * 128, nb = blockIdx.x * 128;
    const int row_st = tid >> 2, seg = tid & 3;

    f32x4 acc[4][4] = {};

    for (int k0 = 0; k0 < K; k0 += 32) {
        float4 av0 = *(const float4*)(A + (size_t)(mb + row_st) * K + k0 + seg * 8);
        float4 av1 = *(const float4*)(A + (size_t)(mb + row_st + 64) * K + k0 + seg * 8);
        float4 bv0 = *(const float4*)(BT + (size_t)(nb + row_st) * K + k0 + seg * 8);
        float4 bv1 = *(const float4*)(BT + (size_t)(nb + row_st + 64) * K + k0 + seg * 8);
        __syncthreads();
        *(float4*)(As + row_st * 32 + seg * 8) = av0;
        *(float4*)(As + (row_st + 64) * 32 + seg * 8) = av1;
        *(float4*)(Bs + row_st * 32 + seg * 8) = bv0;
        *(float4*)(Bs + (row_st + 64) * 32 + seg * 8) = bv1;
        __syncthreads();
        bf16x8 af[4], bfr[4];
#pragma unroll
        for (int i = 0; i < 4; i++) af[i] = *(const bf16x8*)(As + (wm + i * 16 + r) * 32 + quad * 8);
#pragma unroll
        for (int j = 0; j < 4; j++) bfr[j] = *(const bf16x8*)(Bs + (wn + j * 16 + r) * 32 + quad * 8);
#pragma unroll
        for (int i = 0; i < 4; i++)
#pragma unroll
            for (int j = 0; j < 4; j++) acc[i][j] = mfma16(af[i], bfr[j], acc[i][j]);
    }

    if (MODE == 0) {
        const int col_base = nb + wn;          // multiple of 64 -> one head
        const int region = col_base >> 10;     // 0=q 1=k 2=v
        const int h = (col_base & 1023) >> 6;
#pragma unroll
        for (int i = 0; i < 4; i++) {
#pragma unroll
            for (int g = 0; g < 4; g++) {
                int m = mb + wm + i * 16 + quad * 4 + g;
                int b = m >> 11, t = m & (T_ - 1);
                if (region < 2) {
                    bf16_t* dst = (region == 0 ? Qb : Kb) + ((size_t)((b * H_ + h) * T_ + t)) * 64;
#pragma unroll
                    for (int j = 0; j < 2; j++) {
                        int d = j * 16 + r;
                        float u1 = acc[i][j][g] + bias[col_base + d];
                        float u2 = acc[i][j + 2][g] + bias[col_base + d + 32];
                        float c = cosT[t * HD2_ + d], s = sinT[t * HD2_ + d];
                        float o1 = u1 * c - u2 * s;
                        float o2 = u1 * s + u2 * c;
                        if (region == 0) { o1 *= 0.125f; o2 *= 0.125f; }  // fold 1/sqrt(64) into q
                        dst[d] = (bf16_t)o1;
                        dst[d + 32] = (bf16_t)o2;
                    }
                } else {
#pragma unroll
                    for (int j = 0; j < 4; j++) {
                        int d = j * 16 + r;
                        float v = acc[i][j][g] + bias[col_base + d];
                        VTb[((size_t)((b * H_ + h) * 64 + d)) * T_ + t] = (bf16_t)v;
                    }
                }
            }
        }
    } else {
#pragma unroll
        for (int i = 0; i < 4; i++)
#pragma unroll
            for (int g = 0; g < 4; g++) {
                int m = mb + wm + i * 16 + quad * 4 + g;
#pragma unroll
                for (int j = 0; j < 4; j++) {
                    int col = nb + wn + j * 16 + r;
                    out[(size_t)m * N + col] = acc[i][j][g] + bias[col];
                }
            }
    }
}

// ---------------- flash attention (causal) ----------------
// Qb,Kb: [B,H,T,64] bf16 (Q pre-scaled by 1/8, RoPE applied). VTb: [B,H,64,T] bf16.
// att out: [B*T, 1024] bf16 (c = h*64+d)
__global__ __launch_bounds__(256, 2) void attn64(
    const bf16_t* __restrict__ Qb, const bf16_t* __restrict__ Kb,
    const bf16_t* __restrict__ VTb, bf16_t* __restrict__ att) {
    __shared__ alignas(16) bf16_t Ks[64 * 64];
    __shared__ alignas(16) bf16_t Vs[64 * 64];  // V^T tile: row=d, col=n (xor-swizzled)
    __shared__ alignas(16) bf16_t Ps[4][16 * 88];
    const int tid = threadIdx.x;
    const int w = tid >> 6, lane = tid & 63;
    const int quad = lane >> 4, r = lane & 15;
    const int qtile = blockIdx.x, bh = blockIdx.y;
    const int q0 = qtile * 64;
    const size_t kbase = (size_t)bh * T_ * 64;
    const size_t vbase = (size_t)bh * 64 * T_;

    bf16x8 qf[2];
    {
        int qrow = q0 + w * 16 + r;
        const bf16_t* qp = Qb + kbase + (size_t)qrow * 64 + quad * 8;
        qf[0] = *(const bf16x8*)(qp);
        qf[1] = *(const bf16x8*)(qp + 32);
    }
    f32x4 oacc[4] = {};
    float mstate[4] = {-INFINITY, -INFINITY, -INFINITY, -INFINITY};
    float lstate[4] = {0.f, 0.f, 0.f, 0.f};

    for (int jt = 0; jt <= qtile; jt++) {
        const int j0 = jt * 64;
#pragma unroll
        for (int hf = 0; hf < 2; hf++) {
            int idx = hf * 256 + tid;
            int row = idx >> 3, sq = idx & 7;
            float4 kv = *(const float4*)(Kb + kbase + (size_t)(j0 + row) * 64 + sq * 8);
            float4 vv = *(const float4*)(VTb + vbase + (size_t)row * T_ + j0 + sq * 8);
            *(float4*)(Ks + row * 64 + ((sq ^ (row & 7)) * 8)) = kv;
            *(float4*)(Vs + row * 64 + ((sq ^ (row & 7)) * 8)) = vv;
        }
        __syncthreads();

        // S = Q K^T  (16 rows x 64 cols per wave)
        f32x4 sacc[4];
#pragma unroll
        for (int n0 = 0; n0 < 4; n0++) {
            int krow = n0 * 16 + r;
            bf16x8 kf0 = *(const bf16x8*)(Ks + krow * 64 + ((quad ^ (krow & 7)) * 8));
            bf16x8 kf1 = *(const bf16x8*)(Ks + krow * 64 + (((4 + quad) ^ (krow & 7)) * 8));
            f32x4 z = {0.f, 0.f, 0.f, 0.f};
            z = mfma16(qf[0], kf0, z);
            z = mfma16(qf[1], kf1, z);
            sacc[n0] = z;
        }
        if (jt == qtile) {
#pragma unroll
            for (int n0 = 0; n0 < 4; n0++) {
                int jc = j0 + n0 * 16 + r;
#pragma unroll
                for (int g = 0; g < 4; g++) {
                    int tr = q0 + w * 16 + quad * 4 + g;
                    if (jc > tr) sacc[n0][g] = -INFINITY;
                }
            }
        }
        // online softmax (rows quad*4+g, cols r within each 16-chunk)
        float pv[4][4];
#pragma unroll
        for (int g = 0; g < 4; g++) {
            float vm = fmaxf(fmaxf(sacc[0][g], sacc[1][g]), fmaxf(sacc[2][g], sacc[3][g]));
            vm = fmaxf(vm, __shfl_xor(vm, 1));
            vm = fmaxf(vm, __shfl_xor(vm, 2));
            vm = fmaxf(vm, __shfl_xor(vm, 4));
            vm = fmaxf(vm, __shfl_xor(vm, 8));
            float mnew = fmaxf(mstate[g], vm);
            float alpha = exp2f((mstate[g] - mnew) * LOG2E);
            float rs = 0.f;
#pragma unroll
            for (int n0 = 0; n0 < 4; n0++) {
                float p = exp2f((sacc[n0][g] - mnew) * LOG2E);
                pv[n0][g] = p;
                rs += p;
            }
            rs += __shfl_xor(rs, 1);
            rs += __shfl_xor(rs, 2);
            rs += __shfl_xor(rs, 4);
            rs += __shfl_xor(rs, 8);
            lstate[g] = lstate[g] * alpha + rs;
            mstate[g] = mnew;
#pragma unroll
            for (int d0 = 0; d0 < 4; d0++) oacc[d0][g] *= alpha;
        }
        // P: C-layout -> LDS -> A-layout
#pragma unroll
        for (int n0 = 0; n0 < 4; n0++)
#pragma unroll
            for (int g = 0; g < 4; g++)
                Ps[w][(quad * 4 + g) * 88 + n0 * 16 + r] = (bf16_t)pv[n0][g];

        bf16x8 pf0 = *(const bf16x8*)(&Ps[w][r * 88 + quad * 8]);
        bf16x8 pf1 = *(const bf16x8*)(&Ps[w][r * 88 + 32 + quad * 8]);
#pragma unroll
        for (int d0 = 0; d0 < 4; d0++) {
            int vrow = d0 * 16 + r;
            bf16x8 vf0 = *(const bf16x8*)(Vs + vrow * 64 + ((quad ^ (vrow & 7)) * 8));
            bf16x8 vf1 = *(const bf16x8*)(Vs + vrow * 64 + (((4 + quad) ^ (vrow & 7)) * 8));
            oacc[d0] = mfma16(pf0, vf0, oacc[d0]);
            oacc[d0] = mfma16(pf1, vf1, oacc[d0]);
        }
        __syncthreads();
    }
    // epilogue: normalize, write att[b*T+t][h*64+d]
    int b = bh >> 4, h = bh & 15;
#pragma unroll
    for (int g = 0; g < 4; g++) {
        int t = q0 + w * 16 + quad * 4 + g;
        float inv = 1.f / lstate[g];
        bf16_t* dst = att + ((size_t)(b * T_ + t)) * 1024 + h * 64;
#pragma unroll
        for (int d0 = 0; d0 < 4; d0++) dst[d0 * 16 + r] = (bf16_t)(oacc[d0][g] * inv);
    }
}

// ---------------- launch ----------------
extern "C" void kernel_launch(void* const* d_in, const int* in_sizes, int n_in,
                              void* d_out, int out_size, void* d_ws, size_t ws_size,
                              hipStream_t stream) {
    const float* x = (const float*)d_in[0];
    const float* fcos = (const float*)d_in[1];
    const float* fsin = (const float*)d_in[2];
    const float* Wqkv = (const float*)d_in[3];
    const float* bqkv = (const float*)d_in[4];
    const float* Wproj = (const float*)d_in[5];
    const float* bproj = (const float*)d_in[6];
    float* out = (float*)d_out;

    uint8_t* p = (uint8_t*)d_ws;
    size_t need = 0;
    auto take = [&](size_t bytes) {
        void* q = p;
        size_t pad = (bytes + 255) & ~(size_t)255;
        p += pad;
        need += pad;
        return q;
    };
    bf16_t* xb = (bf16_t*)take((size_t)M_ * C_ * 2);         // 8 MB
    bf16_t* wqkvT = (bf16_t*)take((size_t)3 * C_ * C_ * 2);  // 6 MB
    bf16_t* wprojT = (bf16_t*)take((size_t)C_ * C_ * 2);     // 2 MB
    bf16_t* Qb = (bf16_t*)take((size_t)B_ * H_ * T_ * 64 * 2);
    bf16_t* Kb = (bf16_t*)take((size_t)B_ * H_ * T_ * 64 * 2);
    bf16_t* VTb = (bf16_t*)take((size_t)B_ * H_ * 64 * T_ * 2);
    bf16_t* attb = (bf16_t*)take((size_t)M_ * C_ * 2);
    if (ws_size < need) return;  // fail loudly (zeros) rather than corrupt

    // prep
    cast_f32_to_bf16<<<(M_ * C_ / 4 + 255) / 256, 256, 0, stream>>>(x, xb, M_ * C_ / 4);
    transpose_cast<<<dim3(3 * C_ / 32, C_ / 32), dim3(32, 8), 0, stream>>>(Wqkv, wqkvT, C_, 3 * C_);
    transpose_cast<<<dim3(C_ / 32, C_ / 32), dim3(32, 8), 0, stream>>>(Wproj, wprojT, C_, C_);

    // QKV GEMM + bias + RoPE + scatter
    gemm128<0><<<dim3(3 * C_ / 128, M_ / 128), 256, 0, stream>>>(
        xb, wqkvT, bqkv, 3 * C_, C_, Qb, Kb, VTb, fcos, fsin, nullptr);

    // flash attention
    attn64<<<dim3(T_ / 64, B_ * H_), 256, 0, stream>>>(Qb, Kb, VTb, attb);

    // output projection
    gemm128<1><<<dim3(C_ / 128, M_ / 128), 256, 0, stream>>>(
        attb, wprojT, bproj, C_, C_, nullptr, nullptr, nullptr, nullptr, nullptr, out);
}